// Round 3
// baseline (2234.312 us; speedup 1.0000x reference)
//
#include <hip/hip_runtime.h>
#include <math.h>

#define BATCH  2
#define SEQ    2048
#define NH     16
#define DMODEL 1024
#define DHEAD  64
#define KT     16   // keys per tile per split (attention)

// ---------------------------------------------------------------------------
// SGEMM: Y[M,N] = X[M,K] @ W[N,K]^T + bias[N]
// Both X and W are row-major with K contiguous (the "TN" layout) -> dot of rows.
// BM=BN=64, BK=32, 256 threads, 4x4 micro-tile. Grid: (N/64, M/64, z)
// ---------------------------------------------------------------------------
__device__ __forceinline__ void gemm_body(
    const float* __restrict__ X, const float* __restrict__ W,
    const float* __restrict__ bias, float* __restrict__ Y,
    const int K, const int N) {
  // stride 68 floats = 272B: keeps 16B alignment for float4 LDS reads,
  // breaks the worst write-bank pattern (<=4-way on writes, negligible).
  __shared__ float As[32][68];
  __shared__ float Bs[32][68];
  const int tid = threadIdx.x;
  const int tx = tid & 15;          // n-group (4 cols each)
  const int ty = tid >> 4;          // m-group (4 rows each)
  const int m0 = blockIdx.y << 6;
  const int n0 = blockIdx.x << 6;
  const int lr = tid >> 3;          // 0..31 row-in-half-tile for loads
  const int lk = (tid & 7) << 2;    // 0,4,...,28 k-offset for loads

  float acc[4][4] = {};

  const float* xp0 = X + (size_t)(m0 + lr) * K + lk;
  const float* xp1 = X + (size_t)(m0 + lr + 32) * K + lk;
  const float* wp0 = W + (size_t)(n0 + lr) * K + lk;
  const float* wp1 = W + (size_t)(n0 + lr + 32) * K + lk;

  for (int k0 = 0; k0 < K; k0 += 32) {
    const float4 a0 = *(const float4*)(xp0 + k0);
    const float4 a1 = *(const float4*)(xp1 + k0);
    const float4 b0 = *(const float4*)(wp0 + k0);
    const float4 b1 = *(const float4*)(wp1 + k0);
    __syncthreads();  // previous iteration's compute must finish before overwrite
    As[lk + 0][lr] = a0.x; As[lk + 1][lr] = a0.y;
    As[lk + 2][lr] = a0.z; As[lk + 3][lr] = a0.w;
    As[lk + 0][lr + 32] = a1.x; As[lk + 1][lr + 32] = a1.y;
    As[lk + 2][lr + 32] = a1.z; As[lk + 3][lr + 32] = a1.w;
    Bs[lk + 0][lr] = b0.x; Bs[lk + 1][lr] = b0.y;
    Bs[lk + 2][lr] = b0.z; Bs[lk + 3][lr] = b0.w;
    Bs[lk + 0][lr + 32] = b1.x; Bs[lk + 1][lr + 32] = b1.y;
    Bs[lk + 2][lr + 32] = b1.z; Bs[lk + 3][lr + 32] = b1.w;
    __syncthreads();
#pragma unroll
    for (int kk = 0; kk < 32; ++kk) {
      const float4 av = *(const float4*)&As[kk][ty << 2];
      const float4 bv = *(const float4*)&Bs[kk][tx << 2];
      const float a4[4] = {av.x, av.y, av.z, av.w};
      const float b4[4] = {bv.x, bv.y, bv.z, bv.w};
#pragma unroll
      for (int i = 0; i < 4; ++i)
#pragma unroll
        for (int j = 0; j < 4; ++j) acc[i][j] += a4[i] * b4[j];
    }
  }

  const float4 bb = *(const float4*)&bias[n0 + (tx << 2)];
  const float b4[4] = {bb.x, bb.y, bb.z, bb.w};
#pragma unroll
  for (int i = 0; i < 4; ++i) {
    float4 o;
    o.x = acc[i][0] + b4[0];
    o.y = acc[i][1] + b4[1];
    o.z = acc[i][2] + b4[2];
    o.w = acc[i][3] + b4[3];
    *(float4*)(Y + (size_t)(m0 + (ty << 2) + i) * N + n0 + (tx << 2)) = o;
  }
}

__global__ __launch_bounds__(256) void qkv_gemm(
    const float* __restrict__ hs,
    const float* __restrict__ wq, const float* __restrict__ wk,
    const float* __restrict__ wv,
    const float* __restrict__ bq, const float* __restrict__ bk,
    const float* __restrict__ bv,
    float* __restrict__ Qb, float* __restrict__ Kb, float* __restrict__ Vb) {
  const int z = blockIdx.z;
  const float* W = (z == 0) ? wq : (z == 1) ? wk : wv;
  const float* b = (z == 0) ? bq : (z == 1) ? bk : bv;
  float* Y = (z == 0) ? Qb : (z == 1) ? Kb : Vb;
  gemm_body(hs, W, b, Y, DMODEL, DMODEL);
}

__global__ __launch_bounds__(256) void oproj_gemm(
    const float* __restrict__ X, const float* __restrict__ wo,
    const float* __restrict__ bo, float* __restrict__ Y) {
  gemm_body(X, wo, bo, Y, DMODEL, DMODEL);
}

// ---------------------------------------------------------------------------
// Flash-style attention over natural [B, L, D] Q/K/V layout (head h = cols
// h*64..h*64+63).  Block = 256 threads = 128 query rows x 2 key-splits
// (split = lane&1, so the split-pair shares a wave -> shfl merge).
// Split s covers keys [1024*s, 1024*s+1024) in tiles of KT.
// Grid: (SEQ/128, NH, BATCH) = (16,16,2) = 512 blocks -> 2 waves/SIMD.
// ---------------------------------------------------------------------------
__global__ __launch_bounds__(256, 2) void attn_kernel(
    const float* __restrict__ Q, const float* __restrict__ Kg,
    const float* __restrict__ Vg, float* __restrict__ O) {
  __shared__ float Ks[2][KT][DHEAD];
  __shared__ float Vs[2][KT][DHEAD];
  const int tid = threadIdx.x;
  const int lane = tid & 63;
  const int wid = tid >> 6;
  const int split = lane & 1;
  const int row_local = (wid << 5) + (lane >> 1);  // 0..127
  const int b = blockIdx.z;
  const int h = blockIdx.y;
  const int qrow = (blockIdx.x << 7) + row_local;
  const float scale = 0.125f;  // 1/sqrt(64)

  // q row -> registers (64 VGPR)
  const float* qp = Q + ((size_t)(b * SEQ + qrow) * DMODEL) + h * DHEAD;
  float q[DHEAD];
#pragma unroll
  for (int d4 = 0; d4 < 16; ++d4) {
    const float4 v = *(const float4*)(qp + (d4 << 2));
    q[(d4 << 2) + 0] = v.x; q[(d4 << 2) + 1] = v.y;
    q[(d4 << 2) + 2] = v.z; q[(d4 << 2) + 3] = v.w;
  }
  float o[DHEAD];
#pragma unroll
  for (int d = 0; d < DHEAD; ++d) o[d] = 0.f;
  float mrun = -INFINITY, lrun = 0.f;

  const size_t bh_off = ((size_t)b * SEQ) * DMODEL + h * DHEAD;

  for (int t = 0; t < 1024 / KT; ++t) {
    __syncthreads();
    // cooperative load: 2 splits * KT keys * 64 floats * {K,V}
    // = 2*KT*16*2 float4s; 256 threads -> (2*KT*16*2)/256 float4 each.
#pragma unroll
    for (int c = 0; c < (2 * KT * 16 * 2) / 256; ++c) {
      const int g = c * 256 + tid;             // 0 .. 2*KT*16*2-1
      const int mat = g / (2 * KT * 16);       // 0=K, 1=V
      const int rr = (g >> 4) & (2 * KT - 1);  // ls*KT + key
      const int d4 = g & 15;
      const int ls = rr / KT;
      const int key = rr % KT;
      const int gkey = ls * 1024 + t * KT + key;
      const float* src =
          (mat ? Vg : Kg) + bh_off + (size_t)gkey * DMODEL + (d4 << 2);
      float* dst = (mat ? &Vs[0][0][0] : &Ks[0][0][0]) + (rr << 6) + (d4 << 2);
      *(float4*)dst = *(const float4*)src;
    }
    __syncthreads();

    // phase 1: scores for this tile (two-pass softmax within tile)
    float sreg[KT];
    float tmax = -INFINITY;
#pragma unroll
    for (int j = 0; j < KT; ++j) {
      const float4* kp = (const float4*)&Ks[split][j][0];
      float s0 = 0.f, s1 = 0.f, s2 = 0.f, s3 = 0.f;
#pragma unroll
      for (int d4 = 0; d4 < 16; ++d4) {
        const float4 kv = kp[d4];
        s0 += q[(d4 << 2) + 0] * kv.x;
        s1 += q[(d4 << 2) + 1] * kv.y;
        s2 += q[(d4 << 2) + 2] * kv.z;
        s3 += q[(d4 << 2) + 3] * kv.w;
      }
      const float sv = ((s0 + s1) + (s2 + s3)) * scale;
      sreg[j] = sv;
      tmax = fmaxf(tmax, sv);
    }
    const float mnew = fmaxf(mrun, tmax);
    const float corr = __expf(mrun - mnew);  // exp(-inf)=0 on first tile
    lrun *= corr;
#pragma unroll
    for (int d = 0; d < DHEAD; ++d) o[d] *= corr;
#pragma unroll
    for (int j = 0; j < KT; ++j) {
      const float p = __expf(sreg[j] - mnew);
      lrun += p;
      sreg[j] = p;
    }
    // phase 2: PV accumulate
#pragma unroll
    for (int j = 0; j < KT; ++j) {
      const float4* vp = (const float4*)&Vs[split][j][0];
      const float p = sreg[j];
#pragma unroll
      for (int d4 = 0; d4 < 16; ++d4) {
        const float4 vv = vp[d4];
        o[(d4 << 2) + 0] += p * vv.x;
        o[(d4 << 2) + 1] += p * vv.y;
        o[(d4 << 2) + 2] += p * vv.z;
        o[(d4 << 2) + 3] += p * vv.w;
      }
    }
    mrun = mnew;
  }

  // merge the split pair (lanes 2r / 2r+1) via shfl
  const float m2 = __shfl_xor(mrun, 1);
  const float l2 = __shfl_xor(lrun, 1);
  const float mn = fmaxf(mrun, m2);
  const float e1 = __expf(mrun - mn);
  const float e2 = __expf(m2 - mn);
  const float denom = lrun * e1 + l2 * e2;
  const float inv = 1.0f / denom;
#pragma unroll
  for (int d = 0; d < DHEAD; ++d) {
    o[d] = (o[d] * e1 + __shfl_xor(o[d], 1) * e2) * inv;
  }
  // both lanes of the pair hold the full row; each stores its half
  float* op = O + ((size_t)(b * SEQ + qrow) * DMODEL) + h * DHEAD;
#pragma unroll
  for (int d4 = 0; d4 < 16; ++d4) {
    const bool mine = (d4 < 8) ? (split == 0) : (split == 1);
    if (mine) {
      float4 v;
      v.x = o[(d4 << 2) + 0]; v.y = o[(d4 << 2) + 1];
      v.z = o[(d4 << 2) + 2]; v.w = o[(d4 << 2) + 3];
      *(float4*)(op + (d4 << 2)) = v;
    }
  }
}

// ---------------------------------------------------------------------------
extern "C" void kernel_launch(void* const* d_in, const int* in_sizes, int n_in,
                              void* d_out, int out_size, void* d_ws,
                              size_t ws_size, hipStream_t stream) {
  const float* hs = (const float*)d_in[0];
  const float* wq = (const float*)d_in[1];
  const float* bq = (const float*)d_in[2];
  const float* wk = (const float*)d_in[3];
  const float* bk = (const float*)d_in[4];
  const float* wv = (const float*)d_in[5];
  const float* bv = (const float*)d_in[6];
  const float* wo = (const float*)d_in[7];
  const float* bo = (const float*)d_in[8];
  float* out = (float*)d_out;

  // workspace: Q, K, V, Att each [B, L, D] fp32 = 16 MiB -> 64 MiB total
  const size_t elems = (size_t)BATCH * SEQ * DMODEL;  // 4M
  float* Qb = (float*)d_ws;
  float* Kb = Qb + elems;
  float* Vb = Kb + elems;
  float* Ab = Vb + elems;

  // QKV projections (fused via grid.z)
  qkv_gemm<<<dim3(DMODEL / 64, (BATCH * SEQ) / 64, 3), 256, 0, stream>>>(
      hs, wq, wk, wv, bq, bk, bv, Qb, Kb, Vb);
  // attention
  attn_kernel<<<dim3(SEQ / 128, NH, BATCH), 256, 0, stream>>>(Qb, Kb, Vb, Ab);
  // output projection
  oproj_gemm<<<dim3(DMODEL / 64, (BATCH * SEQ) / 64, 1), 256, 0, stream>>>(
      Ab, wo, bo, out);
}

// Round 4
// 601.025 us; speedup vs baseline: 3.7175x; 3.7175x over previous
//
#include <hip/hip_runtime.h>
#include <math.h>

#define BATCH  2
#define SEQ    2048
#define NH     16
#define DMODEL 1024
#define DHEAD  64

typedef short short8 __attribute__((ext_vector_type(8)));
typedef float f32x4 __attribute__((ext_vector_type(4)));

// Q pre-scale: 1/sqrt(64) * log2(e)  -> softmax via exp2
#define QSCALE 0.18033688011112042f

__device__ __forceinline__ ushort f2bf(float f) {
  // round-to-nearest-even f32 -> bf16 (finite inputs only)
  unsigned int u = __builtin_bit_cast(unsigned int, f);
  u = (u + 0x7FFFu + ((u >> 16) & 1u)) >> 16;
  return (ushort)u;
}

// ---------------------------------------------------------------------------
// fp32 SGEMM body: Y = X[M,K] @ W[N,K]^T + bias (TN layout). Proven ~135 TF.
// ---------------------------------------------------------------------------
__device__ __forceinline__ void gemm_core(
    const float* __restrict__ X, const float* __restrict__ W,
    float (&acc)[4][4], const int K) {
  __shared__ float As[32][68];
  __shared__ float Bs[32][68];
  const int tid = threadIdx.x;
  const int tx = tid & 15;
  const int ty = tid >> 4;
  const int m0 = blockIdx.y << 6;
  const int n0 = blockIdx.x << 6;
  const int lr = tid >> 3;
  const int lk = (tid & 7) << 2;

  const float* xp0 = X + (size_t)(m0 + lr) * K + lk;
  const float* xp1 = X + (size_t)(m0 + lr + 32) * K + lk;
  const float* wp0 = W + (size_t)(n0 + lr) * K + lk;
  const float* wp1 = W + (size_t)(n0 + lr + 32) * K + lk;

  for (int k0 = 0; k0 < K; k0 += 32) {
    const float4 a0 = *(const float4*)(xp0 + k0);
    const float4 a1 = *(const float4*)(xp1 + k0);
    const float4 b0 = *(const float4*)(wp0 + k0);
    const float4 b1 = *(const float4*)(wp1 + k0);
    __syncthreads();
    As[lk + 0][lr] = a0.x; As[lk + 1][lr] = a0.y;
    As[lk + 2][lr] = a0.z; As[lk + 3][lr] = a0.w;
    As[lk + 0][lr + 32] = a1.x; As[lk + 1][lr + 32] = a1.y;
    As[lk + 2][lr + 32] = a1.z; As[lk + 3][lr + 32] = a1.w;
    Bs[lk + 0][lr] = b0.x; Bs[lk + 1][lr] = b0.y;
    Bs[lk + 2][lr] = b0.z; Bs[lk + 3][lr] = b0.w;
    Bs[lk + 0][lr + 32] = b1.x; Bs[lk + 1][lr + 32] = b1.y;
    Bs[lk + 2][lr + 32] = b1.z; Bs[lk + 3][lr + 32] = b1.w;
    __syncthreads();
#pragma unroll
    for (int kk = 0; kk < 32; ++kk) {
      const float4 av = *(const float4*)&As[kk][ty << 2];
      const float4 bv = *(const float4*)&Bs[kk][tx << 2];
      const float a4[4] = {av.x, av.y, av.z, av.w};
      const float b4[4] = {bv.x, bv.y, bv.z, bv.w};
#pragma unroll
      for (int i = 0; i < 4; ++i)
#pragma unroll
        for (int j = 0; j < 4; ++j) acc[i][j] += a4[i] * b4[j];
    }
  }
}

// fp32-out variant (O-projection -> d_out)
__global__ __launch_bounds__(256) void oproj_gemm(
    const float* __restrict__ X, const float* __restrict__ wo,
    const float* __restrict__ bo, float* __restrict__ Y) {
  float acc[4][4] = {};
  gemm_core(X, wo, acc, DMODEL);
  const int tid = threadIdx.x;
  const int tx = tid & 15, ty = tid >> 4;
  const int m0 = blockIdx.y << 6, n0 = blockIdx.x << 6;
  const float4 bb = *(const float4*)&bo[n0 + (tx << 2)];
  const float b4[4] = {bb.x, bb.y, bb.z, bb.w};
#pragma unroll
  for (int i = 0; i < 4; ++i) {
    float4 o;
    o.x = acc[i][0] + b4[0];
    o.y = acc[i][1] + b4[1];
    o.z = acc[i][2] + b4[2];
    o.w = acc[i][3] + b4[3];
    *(float4*)(Y + (size_t)(m0 + (ty << 2) + i) * DMODEL + n0 + (tx << 2)) = o;
  }
}

// bf16-out variant (QKV projections; Q gets QSCALE folded in)
__global__ __launch_bounds__(256) void qkv_gemm(
    const float* __restrict__ hs,
    const float* __restrict__ wq, const float* __restrict__ wk,
    const float* __restrict__ wv,
    const float* __restrict__ bq, const float* __restrict__ bk,
    const float* __restrict__ bv,
    ushort* __restrict__ Qb, ushort* __restrict__ Kb,
    ushort* __restrict__ Vb) {
  const int z = blockIdx.z;
  const float* W = (z == 0) ? wq : (z == 1) ? wk : wv;
  const float* bias = (z == 0) ? bq : (z == 1) ? bk : bv;
  ushort* Y = (z == 0) ? Qb : (z == 1) ? Kb : Vb;
  const float oscale = (z == 0) ? QSCALE : 1.0f;

  float acc[4][4] = {};
  gemm_core(hs, W, acc, DMODEL);
  const int tid = threadIdx.x;
  const int tx = tid & 15, ty = tid >> 4;
  const int m0 = blockIdx.y << 6, n0 = blockIdx.x << 6;
  const float4 bb = *(const float4*)&bias[n0 + (tx << 2)];
  const float b4[4] = {bb.x, bb.y, bb.z, bb.w};
#pragma unroll
  for (int i = 0; i < 4; ++i) {
    ushort4 w;
    w.x = f2bf((acc[i][0] + b4[0]) * oscale);
    w.y = f2bf((acc[i][1] + b4[1]) * oscale);
    w.z = f2bf((acc[i][2] + b4[2]) * oscale);
    w.w = f2bf((acc[i][3] + b4[3]) * oscale);
    *(ushort4*)(Y + (size_t)(m0 + (ty << 2) + i) * DMODEL + n0 + (tx << 2)) = w;
  }
}

// ---------------------------------------------------------------------------
// MFMA flash attention. bf16 Q/K/V (Q pre-scaled), fp32 out.
// Block: 512 thr = 8 waves; wave owns 16 q-rows; KT=64 keys per tile.
// Grid: (2048/128, 16, 2) = 512 blocks.
//
// mfma_f32_16x16x32_bf16 layouts (per guide §3):
//   A: a[j] = A[lane%16][(lane/16)*8 + j]
//   B: b[j] = B[(lane/16)*8 + j][lane%16]
//   C/D: col = lane&15, row = (lane>>4)*4 + reg
//
// LDS: K [64key][72] (144B rows: even 8-group spread for b128)
//      Vt[64d ][72] transposed, key XOR-swizzled by (d>>3)<<3 (conflict-free
//                   u16 scatter writes: 64 lanes -> 32 distinct banks)
//      P  per-wave [16q][72]
// ---------------------------------------------------------------------------
__global__ __launch_bounds__(512, 4) void attn_mfma(
    const ushort* __restrict__ Q, const ushort* __restrict__ K,
    const ushort* __restrict__ V, float* __restrict__ O) {
  __shared__ ushort Klds[64][72];
  __shared__ ushort Vlds[64][72];
  __shared__ ushort Plds[8][16][72];

  const int tid = threadIdx.x;
  const int lane = tid & 63;
  const int wv = tid >> 6;      // wave 0..7
  const int m16 = lane & 15;
  const int g4 = lane >> 4;     // 0..3
  const int b = blockIdx.z;
  const int h = blockIdx.y;
  const int q0 = (blockIdx.x << 7) + (wv << 4);  // wave's 16-row q base

  const size_t base = ((size_t)b * SEQ) * DMODEL + h * DHEAD;  // elem offset

  // --- Q fragments (2 k-steps of 32 over DHEAD=64), rows = m16 ---
  short8 qf[2];
  {
    const ushort* qp = Q + base + (size_t)(q0 + m16) * DMODEL + (g4 << 3);
    qf[0] = *(const short8*)(qp);
    qf[1] = *(const short8*)(qp + 32);
  }

  f32x4 oacc[4];  // [dt], 4 q-rows per lane in vector elems
#pragma unroll
  for (int dt = 0; dt < 4; ++dt) oacc[dt] = (f32x4){0.f, 0.f, 0.f, 0.f};
  float mrow[4] = {-1e30f, -1e30f, -1e30f, -1e30f};
  float lrow[4] = {0.f, 0.f, 0.f, 0.f};

  // staging map: 512 threads, key = tid>>3 (64), seg = tid&7 (8 x 16B)
  const int skey = tid >> 3;
  const int sseg = tid & 7;
  const ushort* kgp = K + base + (size_t)skey * DMODEL + (sseg << 3);
  const ushort* vgp = V + base + (size_t)skey * DMODEL + (sseg << 3);
  const int vswz_key = skey ^ (sseg << 3);  // d>>3 == sseg for this thread

  for (int kt = 0; kt < SEQ / 64; ++kt) {
    const size_t koff = (size_t)kt * 64 * DMODEL;
    const short8 kvec = *(const short8*)(kgp + koff);
    const short8 vvec = *(const short8*)(vgp + koff);
    __syncthreads();  // previous tile fully consumed
    *(short8*)&Klds[skey][sseg << 3] = kvec;
#pragma unroll
    for (int i = 0; i < 8; ++i)
      Vlds[(sseg << 3) + i][vswz_key] = ((const ushort*)&vvec)[i];
    __syncthreads();

    // --- S = Q * K^T for 4 key sub-tiles of 16 ---
    f32x4 s[4];
#pragma unroll
    for (int kt2 = 0; kt2 < 4; ++kt2) s[kt2] = (f32x4){0.f, 0.f, 0.f, 0.f};
#pragma unroll
    for (int ks = 0; ks < 2; ++ks) {
#pragma unroll
      for (int kt2 = 0; kt2 < 4; ++kt2) {
        const short8 kf =
            *(const short8*)&Klds[(kt2 << 4) + m16][(ks << 5) + (g4 << 3)];
        s[kt2] =
            __builtin_amdgcn_mfma_f32_16x16x32_bf16(qf[ks], kf, s[kt2], 0, 0, 0);
      }
    }

    // --- online softmax (rows r: q = g4*4 + r), exp2 domain ---
#pragma unroll
    for (int r = 0; r < 4; ++r) {
      float t = fmaxf(fmaxf(s[0][r], s[1][r]), fmaxf(s[2][r], s[3][r]));
      t = fmaxf(t, __shfl_xor(t, 1));
      t = fmaxf(t, __shfl_xor(t, 2));
      t = fmaxf(t, __shfl_xor(t, 4));
      t = fmaxf(t, __shfl_xor(t, 8));
      const float mn = fmaxf(mrow[r], t);
      const float corr = exp2f(mrow[r] - mn);
      mrow[r] = mn;
      float ps = 0.f;
#pragma unroll
      for (int kt2 = 0; kt2 < 4; ++kt2) {
        const float p = exp2f(s[kt2][r] - mn);
        s[kt2][r] = p;
        ps += p;
      }
      ps += __shfl_xor(ps, 1);
      ps += __shfl_xor(ps, 2);
      ps += __shfl_xor(ps, 4);
      ps += __shfl_xor(ps, 8);
      lrow[r] = lrow[r] * corr + ps;
#pragma unroll
      for (int dt = 0; dt < 4; ++dt) oacc[dt][r] *= corr;
    }

    // --- P -> per-wave LDS (bf16), D-layout -> A-layout transpose ---
#pragma unroll
    for (int kt2 = 0; kt2 < 4; ++kt2)
#pragma unroll
      for (int r = 0; r < 4; ++r)
        Plds[wv][(g4 << 2) + r][(kt2 << 4) + m16] = f2bf(s[kt2][r]);

    // --- O += P * V --- (same-wave LDS RAW: compiler orders via lgkmcnt)
    short8 pf[2];
#pragma unroll
    for (int ks = 0; ks < 2; ++ks)
      pf[ks] = *(const short8*)&Plds[wv][m16][(ks << 5) + (g4 << 3)];
#pragma unroll
    for (int dt = 0; dt < 4; ++dt) {
      const int d = (dt << 4) + m16;
      const int swz = (d >> 3) << 3;
#pragma unroll
      for (int ks = 0; ks < 2; ++ks) {
        const short8 vf =
            *(const short8*)&Vlds[d][((ks << 5) + (g4 << 3)) ^ swz];
        oacc[dt] =
            __builtin_amdgcn_mfma_f32_16x16x32_bf16(pf[ks], vf, oacc[dt], 0, 0, 0);
      }
    }
  }

  // --- epilogue: O / l ---
#pragma unroll
  for (int r = 0; r < 4; ++r) {
    const float inv = 1.0f / lrow[r];
    const size_t row = (size_t)(q0 + (g4 << 2) + r);
    float* op = O + ((size_t)b * SEQ + row) * DMODEL + h * DHEAD + m16;
#pragma unroll
    for (int dt = 0; dt < 4; ++dt) op[dt << 4] = oacc[dt][r] * inv;
  }
}

// ---------------------------------------------------------------------------
extern "C" void kernel_launch(void* const* d_in, const int* in_sizes, int n_in,
                              void* d_out, int out_size, void* d_ws,
                              size_t ws_size, hipStream_t stream) {
  const float* hs = (const float*)d_in[0];
  const float* wq = (const float*)d_in[1];
  const float* bq = (const float*)d_in[2];
  const float* wk = (const float*)d_in[3];
  const float* bk = (const float*)d_in[4];
  const float* wv = (const float*)d_in[5];
  const float* bv = (const float*)d_in[6];
  const float* wo = (const float*)d_in[7];
  const float* bo = (const float*)d_in[8];
  float* out = (float*)d_out;

  // ws: Q,K,V bf16 (8 MiB each) + attn out fp32 (16 MiB) = 40 MiB
  const size_t elems = (size_t)BATCH * SEQ * DMODEL;  // 4M
  ushort* Qb = (ushort*)d_ws;
  ushort* Kb = Qb + elems;
  ushort* Vb = Kb + elems;
  float* Ab = (float*)(Vb + elems);

  qkv_gemm<<<dim3(DMODEL / 64, (BATCH * SEQ) / 64, 3), 256, 0, stream>>>(
      hs, wq, wk, wv, bq, bk, bv, Qb, Kb, Vb);
  attn_mfma<<<dim3(SEQ / 128, NH, BATCH), 512, 0, stream>>>(Qb, Kb, Vb, Ab);
  oproj_gemm<<<dim3(DMODEL / 64, (BATCH * SEQ) / 64, 1), 256, 0, stream>>>(
      Ab, wo, bo, out);
}

// Round 5
// 294.273 us; speedup vs baseline: 7.5926x; 2.0424x over previous
//
#include <hip/hip_runtime.h>
#include <math.h>

#define BATCH  2
#define SEQ    2048
#define NH     16
#define DMODEL 1024
#define DHEAD  64

typedef short short8 __attribute__((ext_vector_type(8)));
typedef float f32x4 __attribute__((ext_vector_type(4)));

// Q pre-scale: 1/sqrt(64) * log2(e)  -> softmax via exp2
#define QSCALE 0.18033688011112042f

__device__ __forceinline__ ushort f2bf(float f) {
  // round-to-nearest-even f32 -> bf16 (finite inputs only)
  unsigned int u = __builtin_bit_cast(unsigned int, f);
  u = (u + 0x7FFFu + ((u >> 16) & 1u)) >> 16;
  return (ushort)u;
}

// ---------------------------------------------------------------------------
// Cast fp32 -> bf16: z=0 hs (4M elems), z=1..3 wq/wk/wv (1M each).
// ---------------------------------------------------------------------------
__global__ __launch_bounds__(256) void cast_all(
    const float* __restrict__ hs, const float* __restrict__ wq,
    const float* __restrict__ wk, const float* __restrict__ wv,
    ushort* __restrict__ hsb, ushort* __restrict__ wqb,
    ushort* __restrict__ wkb, ushort* __restrict__ wvb) {
  const int z = blockIdx.y;
  const float* s = (z == 0) ? hs : (z == 1) ? wq : (z == 2) ? wk : wv;
  ushort* d = (z == 0) ? hsb : (z == 1) ? wqb : (z == 2) ? wkb : wvb;
  const int n = (z == 0) ? BATCH * SEQ * DMODEL : DMODEL * DMODEL;
  const int i = (blockIdx.x * 256 + threadIdx.x) * 8;
  if (i < n) {
    const float4 a = *(const float4*)(s + i);
    const float4 b = *(const float4*)(s + i + 4);
    short8 o;
    o[0] = (short)f2bf(a.x); o[1] = (short)f2bf(a.y);
    o[2] = (short)f2bf(a.z); o[3] = (short)f2bf(a.w);
    o[4] = (short)f2bf(b.x); o[5] = (short)f2bf(b.y);
    o[6] = (short)f2bf(b.z); o[7] = (short)f2bf(b.w);
    *(short8*)(d + i) = o;
  }
}

// ---------------------------------------------------------------------------
// bf16 MFMA GEMM: Y[M,1024] = bf16(X)[M,1024] @ bf16(W)[1024,1024]^T + bias,
// output bf16 (Q scaled by QSCALE). Tile 128x128, BK=32, 512 thr = 8 waves
// (2m x 4n), wave tile 64x32 = 4x2 frags of 16x16x32.
// Grid: (1024/128, M/128, 3).
// Fragment conventions identical to the validated attn kernel:
//   A: lane m16 = row, regs = k-octet g4;  B: lane m16 = col, regs = k-octet.
//   D: col = lane&15, row = (lane>>4)*4 + reg.
// LDS pad to 40 elems/row (80B): staging writes and b128 frag reads both
// spread evenly over the 8 4-bank slots (bankstart = (20*row + 4*seg) % 32).
// ---------------------------------------------------------------------------
__global__ __launch_bounds__(512) void qkv_mfma(
    const ushort* __restrict__ X,
    const ushort* __restrict__ wqb, const ushort* __restrict__ wkb,
    const ushort* __restrict__ wvb,
    const float* __restrict__ bq, const float* __restrict__ bk,
    const float* __restrict__ bv,
    ushort* __restrict__ Qb, ushort* __restrict__ Kb,
    ushort* __restrict__ Vb) {
  const int z = blockIdx.z;
  const ushort* W = (z == 0) ? wqb : (z == 1) ? wkb : wvb;
  const float* bias = (z == 0) ? bq : (z == 1) ? bk : bv;
  ushort* Y = (z == 0) ? Qb : (z == 1) ? Kb : Vb;
  const float oscale = (z == 0) ? QSCALE : 1.0f;

  __shared__ ushort Al[128][40];
  __shared__ ushort Bl[128][40];

  const int tid = threadIdx.x;
  const int lane = tid & 63;
  const int w8 = tid >> 6;       // wave 0..7
  const int wm = w8 >> 2;        // 0..1  (m half)
  const int wn = w8 & 3;         // 0..3  (n quarter)
  const int m16 = lane & 15;
  const int g4 = lane >> 4;
  const int m0 = blockIdx.y << 7;
  const int n0 = blockIdx.x << 7;

  // staging: 512 threads cover 128 rows x 32 cols (one short8 each)
  const int srow = tid >> 2;
  const int sseg = (tid & 3) << 3;  // elem offset 0,8,16,24
  const ushort* ap = X + (size_t)(m0 + srow) * DMODEL + sseg;
  const ushort* wp = W + (size_t)(n0 + srow) * DMODEL + sseg;

  f32x4 acc[4][2];
#pragma unroll
  for (int mi = 0; mi < 4; ++mi)
#pragma unroll
    for (int ni = 0; ni < 2; ++ni) acc[mi][ni] = (f32x4){0.f, 0.f, 0.f, 0.f};

  short8 pa = *(const short8*)(ap);
  short8 pb = *(const short8*)(wp);

  for (int kt = 0; kt < DMODEL / 32; ++kt) {
    __syncthreads();  // previous tile fully consumed
    *(short8*)&Al[srow][sseg] = pa;
    *(short8*)&Bl[srow][sseg] = pb;
    __syncthreads();
    if (kt < DMODEL / 32 - 1) {   // prefetch next tile under the MFMAs
      pa = *(const short8*)(ap + (kt + 1) * 32);
      pb = *(const short8*)(wp + (kt + 1) * 32);
    }
    short8 af[4], bf[2];
#pragma unroll
    for (int mi = 0; mi < 4; ++mi)
      af[mi] = *(const short8*)&Al[(wm << 6) + (mi << 4) + m16][g4 << 3];
#pragma unroll
    for (int ni = 0; ni < 2; ++ni)
      bf[ni] = *(const short8*)&Bl[(wn << 5) + (ni << 4) + m16][g4 << 3];
#pragma unroll
    for (int mi = 0; mi < 4; ++mi)
#pragma unroll
      for (int ni = 0; ni < 2; ++ni)
        acc[mi][ni] = __builtin_amdgcn_mfma_f32_16x16x32_bf16(
            af[mi], bf[ni], acc[mi][ni], 0, 0, 0);
  }

  // epilogue: bias + scale + bf16 store
#pragma unroll
  for (int ni = 0; ni < 2; ++ni) {
    const int col = n0 + (wn << 5) + (ni << 4) + m16;
    const float bv4 = bias[col];
#pragma unroll
    for (int mi = 0; mi < 4; ++mi) {
#pragma unroll
      for (int r = 0; r < 4; ++r) {
        const int row = m0 + (wm << 6) + (mi << 4) + (g4 << 2) + r;
        Y[(size_t)row * DMODEL + col] = f2bf((acc[mi][ni][r] + bv4) * oscale);
      }
    }
  }
}

// ---------------------------------------------------------------------------
// fp32 SGEMM (verbatim round-3 proven body): out = X @ wo^T + bo. ~64 us.
// ---------------------------------------------------------------------------
__global__ __launch_bounds__(256) void oproj_gemm(
    const float* __restrict__ X, const float* __restrict__ W,
    const float* __restrict__ bias, float* __restrict__ Y) {
  __shared__ float As[32][68];
  __shared__ float Bs[32][68];
  const int K = DMODEL, N = DMODEL;
  const int tid = threadIdx.x;
  const int tx = tid & 15;
  const int ty = tid >> 4;
  const int m0 = blockIdx.y << 6;
  const int n0 = blockIdx.x << 6;
  const int lr = tid >> 3;
  const int lk = (tid & 7) << 2;

  float acc[4][4] = {};

  const float* xp0 = X + (size_t)(m0 + lr) * K + lk;
  const float* xp1 = X + (size_t)(m0 + lr + 32) * K + lk;
  const float* wp0 = W + (size_t)(n0 + lr) * K + lk;
  const float* wp1 = W + (size_t)(n0 + lr + 32) * K + lk;

  for (int k0 = 0; k0 < K; k0 += 32) {
    const float4 a0 = *(const float4*)(xp0 + k0);
    const float4 a1 = *(const float4*)(xp1 + k0);
    const float4 b0 = *(const float4*)(wp0 + k0);
    const float4 b1 = *(const float4*)(wp1 + k0);
    __syncthreads();
    As[lk + 0][lr] = a0.x; As[lk + 1][lr] = a0.y;
    As[lk + 2][lr] = a0.z; As[lk + 3][lr] = a0.w;
    As[lk + 0][lr + 32] = a1.x; As[lk + 1][lr + 32] = a1.y;
    As[lk + 2][lr + 32] = a1.z; As[lk + 3][lr + 32] = a1.w;
    Bs[lk + 0][lr] = b0.x; Bs[lk + 1][lr] = b0.y;
    Bs[lk + 2][lr] = b0.z; Bs[lk + 3][lr] = b0.w;
    Bs[lk + 0][lr + 32] = b1.x; Bs[lk + 1][lr + 32] = b1.y;
    Bs[lk + 2][lr + 32] = b1.z; Bs[lk + 3][lr + 32] = b1.w;
    __syncthreads();
#pragma unroll
    for (int kk = 0; kk < 32; ++kk) {
      const float4 av = *(const float4*)&As[kk][ty << 2];
      const float4 bv = *(const float4*)&Bs[kk][tx << 2];
      const float a4[4] = {av.x, av.y, av.z, av.w};
      const float b4[4] = {bv.x, bv.y, bv.z, bv.w};
#pragma unroll
      for (int i = 0; i < 4; ++i)
#pragma unroll
        for (int j = 0; j < 4; ++j) acc[i][j] += a4[i] * b4[j];
    }
  }

  const float4 bb = *(const float4*)&bias[n0 + (tx << 2)];
  const float b4[4] = {bb.x, bb.y, bb.z, bb.w};
#pragma unroll
  for (int i = 0; i < 4; ++i) {
    float4 o;
    o.x = acc[i][0] + b4[0];
    o.y = acc[i][1] + b4[1];
    o.z = acc[i][2] + b4[2];
    o.w = acc[i][3] + b4[3];
    *(float4*)(Y + (size_t)(m0 + (ty << 2) + i) * N + n0 + (tx << 2)) = o;
  }
}

// ---------------------------------------------------------------------------
// MFMA flash attention (verbatim round-4, validated). bf16 Q/K/V, fp32 out.
// ---------------------------------------------------------------------------
__global__ __launch_bounds__(512, 4) void attn_mfma(
    const ushort* __restrict__ Q, const ushort* __restrict__ K,
    const ushort* __restrict__ V, float* __restrict__ O) {
  __shared__ ushort Klds[64][72];
  __shared__ ushort Vlds[64][72];
  __shared__ ushort Plds[8][16][72];

  const int tid = threadIdx.x;
  const int lane = tid & 63;
  const int wv = tid >> 6;      // wave 0..7
  const int m16 = lane & 15;
  const int g4 = lane >> 4;     // 0..3
  const int b = blockIdx.z;
  const int h = blockIdx.y;
  const int q0 = (blockIdx.x << 7) + (wv << 4);  // wave's 16-row q base

  const size_t base = ((size_t)b * SEQ) * DMODEL + h * DHEAD;  // elem offset

  // --- Q fragments (2 k-steps of 32 over DHEAD=64), rows = m16 ---
  short8 qf[2];
  {
    const ushort* qp = Q + base + (size_t)(q0 + m16) * DMODEL + (g4 << 3);
    qf[0] = *(const short8*)(qp);
    qf[1] = *(const short8*)(qp + 32);
  }

  f32x4 oacc[4];  // [dt], 4 q-rows per lane in vector elems
#pragma unroll
  for (int dt = 0; dt < 4; ++dt) oacc[dt] = (f32x4){0.f, 0.f, 0.f, 0.f};
  float mrow[4] = {-1e30f, -1e30f, -1e30f, -1e30f};
  float lrow[4] = {0.f, 0.f, 0.f, 0.f};

  // staging map: 512 threads, key = tid>>3 (64), seg = tid&7 (8 x 16B)
  const int skey = tid >> 3;
  const int sseg = tid & 7;
  const ushort* kgp = K + base + (size_t)skey * DMODEL + (sseg << 3);
  const ushort* vgp = V + base + (size_t)skey * DMODEL + (sseg << 3);
  const int vswz_key = skey ^ (sseg << 3);  // d>>3 == sseg for this thread

  for (int kt = 0; kt < SEQ / 64; ++kt) {
    const size_t koff = (size_t)kt * 64 * DMODEL;
    const short8 kvec = *(const short8*)(kgp + koff);
    const short8 vvec = *(const short8*)(vgp + koff);
    __syncthreads();  // previous tile fully consumed
    *(short8*)&Klds[skey][sseg << 3] = kvec;
#pragma unroll
    for (int i = 0; i < 8; ++i)
      Vlds[(sseg << 3) + i][vswz_key] = ((const ushort*)&vvec)[i];
    __syncthreads();

    // --- S = Q * K^T for 4 key sub-tiles of 16 ---
    f32x4 s[4];
#pragma unroll
    for (int kt2 = 0; kt2 < 4; ++kt2) s[kt2] = (f32x4){0.f, 0.f, 0.f, 0.f};
#pragma unroll
    for (int ks = 0; ks < 2; ++ks) {
#pragma unroll
      for (int kt2 = 0; kt2 < 4; ++kt2) {
        const short8 kf =
            *(const short8*)&Klds[(kt2 << 4) + m16][(ks << 5) + (g4 << 3)];
        s[kt2] =
            __builtin_amdgcn_mfma_f32_16x16x32_bf16(qf[ks], kf, s[kt2], 0, 0, 0);
      }
    }

    // --- online softmax (rows r: q = g4*4 + r), exp2 domain ---
#pragma unroll
    for (int r = 0; r < 4; ++r) {
      float t = fmaxf(fmaxf(s[0][r], s[1][r]), fmaxf(s[2][r], s[3][r]));
      t = fmaxf(t, __shfl_xor(t, 1));
      t = fmaxf(t, __shfl_xor(t, 2));
      t = fmaxf(t, __shfl_xor(t, 4));
      t = fmaxf(t, __shfl_xor(t, 8));
      const float mn = fmaxf(mrow[r], t);
      const float corr = exp2f(mrow[r] - mn);
      mrow[r] = mn;
      float ps = 0.f;
#pragma unroll
      for (int kt2 = 0; kt2 < 4; ++kt2) {
        const float p = exp2f(s[kt2][r] - mn);
        s[kt2][r] = p;
        ps += p;
      }
      ps += __shfl_xor(ps, 1);
      ps += __shfl_xor(ps, 2);
      ps += __shfl_xor(ps, 4);
      ps += __shfl_xor(ps, 8);
      lrow[r] = lrow[r] * corr + ps;
#pragma unroll
      for (int dt = 0; dt < 4; ++dt) oacc[dt][r] *= corr;
    }

    // --- P -> per-wave LDS (bf16), D-layout -> A-layout transpose ---
#pragma unroll
    for (int kt2 = 0; kt2 < 4; ++kt2)
#pragma unroll
      for (int r = 0; r < 4; ++r)
        Plds[wv][(g4 << 2) + r][(kt2 << 4) + m16] = f2bf(s[kt2][r]);

    // --- O += P * V --- (same-wave LDS RAW: compiler orders via lgkmcnt)
    short8 pf[2];
#pragma unroll
    for (int ks = 0; ks < 2; ++ks)
      pf[ks] = *(const short8*)&Plds[wv][m16][(ks << 5) + (g4 << 3)];
#pragma unroll
    for (int dt = 0; dt < 4; ++dt) {
      const int d = (dt << 4) + m16;
      const int swz = (d >> 3) << 3;
#pragma unroll
      for (int ks = 0; ks < 2; ++ks) {
        const short8 vf =
            *(const short8*)&Vlds[d][((ks << 5) + (g4 << 3)) ^ swz];
        oacc[dt] =
            __builtin_amdgcn_mfma_f32_16x16x32_bf16(pf[ks], vf, oacc[dt], 0, 0, 0);
      }
    }
  }

  // --- epilogue: O / l ---
#pragma unroll
  for (int r = 0; r < 4; ++r) {
    const float inv = 1.0f / lrow[r];
    const size_t row = (size_t)(q0 + (g4 << 2) + r);
    float* op = O + ((size_t)b * SEQ + row) * DMODEL + h * DHEAD + m16;
#pragma unroll
    for (int dt = 0; dt < 4; ++dt) op[dt << 4] = oacc[dt][r] * inv;
  }
}

// ---------------------------------------------------------------------------
extern "C" void kernel_launch(void* const* d_in, const int* in_sizes, int n_in,
                              void* d_out, int out_size, void* d_ws,
                              size_t ws_size, hipStream_t stream) {
  const float* hs = (const float*)d_in[0];
  const float* wq = (const float*)d_in[1];
  const float* bq = (const float*)d_in[2];
  const float* wk = (const float*)d_in[3];
  const float* bk = (const float*)d_in[4];
  const float* wv = (const float*)d_in[5];
  const float* bv = (const float*)d_in[6];
  const float* wo = (const float*)d_in[7];
  const float* bo = (const float*)d_in[8];
  float* out = (float*)d_out;

  // ws layout (elems): hsb 4M, wqb/wkb/wvb 1M each, Qb/Kb/Vb 4M each (bf16),
  // Ab 4M fp32  -> 8+6+24+16 = 54 MiB
  const size_t elems = (size_t)BATCH * SEQ * DMODEL;  // 4M
  const size_t welems = (size_t)DMODEL * DMODEL;      // 1M
  ushort* hsb = (ushort*)d_ws;
  ushort* wqb = hsb + elems;
  ushort* wkb = wqb + welems;
  ushort* wvb = wkb + welems;
  ushort* Qb = wvb + welems;
  ushort* Kb = Qb + elems;
  ushort* Vb = Kb + elems;
  float* Ab = (float*)(Vb + elems);

  cast_all<<<dim3((int)(elems / (256 * 8)), 4, 1), 256, 0, stream>>>(
      hs, wq, wk, wv, hsb, wqb, wkb, wvb);
  qkv_mfma<<<dim3(DMODEL / 128, (BATCH * SEQ) / 128, 3), 512, 0, stream>>>(
      hsb, wqb, wkb, wvb, bq, bk, bv, Qb, Kb, Vb);
  attn_mfma<<<dim3(SEQ / 128, NH, BATCH), 512, 0, stream>>>(Qb, Kb, Vb, Ab);
  oproj_gemm<<<dim3(DMODEL / 64, (BATCH * SEQ) / 64, 1), 256, 0, stream>>>(
      Ab, wo, bo, out);
}

// Round 6
// 183.301 us; speedup vs baseline: 12.1893x; 1.6054x over previous
//
#include <hip/hip_runtime.h>
#include <math.h>

#define BATCH  2
#define SEQ    2048
#define NH     16
#define DMODEL 1024
#define DHEAD  64

typedef short short8 __attribute__((ext_vector_type(8)));
typedef float f32x4 __attribute__((ext_vector_type(4)));

// Q pre-scale: 1/sqrt(64) * log2(e)  -> softmax via exp2
#define QSCALE 0.18033688011112042f

__device__ __forceinline__ ushort f2bf(float f) {
  // round-to-nearest-even f32 -> bf16 (finite inputs only)
  unsigned int u = __builtin_bit_cast(unsigned int, f);
  u = (u + 0x7FFFu + ((u >> 16) & 1u)) >> 16;
  return (ushort)u;
}

// ---------------------------------------------------------------------------
// Cast fp32 -> bf16: z=0 hs (4M elems), z=1..4 wq/wk/wv/wo (1M each).
// ---------------------------------------------------------------------------
__global__ __launch_bounds__(256) void cast_all(
    const float* __restrict__ hs, const float* __restrict__ wq,
    const float* __restrict__ wk, const float* __restrict__ wv,
    const float* __restrict__ wo,
    ushort* __restrict__ hsb, ushort* __restrict__ wqb,
    ushort* __restrict__ wkb, ushort* __restrict__ wvb,
    ushort* __restrict__ wob) {
  const int z = blockIdx.y;
  const float* s = (z == 0) ? hs : (z == 1) ? wq : (z == 2) ? wk
                   : (z == 3) ? wv : wo;
  ushort* d = (z == 0) ? hsb : (z == 1) ? wqb : (z == 2) ? wkb
              : (z == 3) ? wvb : wob;
  const int n = (z == 0) ? BATCH * SEQ * DMODEL : DMODEL * DMODEL;
  const int i = (blockIdx.x * 256 + threadIdx.x) * 8;
  if (i < n) {
    const float4 a = *(const float4*)(s + i);
    const float4 b = *(const float4*)(s + i + 4);
    short8 o;
    o[0] = (short)f2bf(a.x); o[1] = (short)f2bf(a.y);
    o[2] = (short)f2bf(a.z); o[3] = (short)f2bf(a.w);
    o[4] = (short)f2bf(b.x); o[5] = (short)f2bf(b.y);
    o[6] = (short)f2bf(b.z); o[7] = (short)f2bf(b.w);
    *(short8*)(d + i) = o;
  }
}

// ---------------------------------------------------------------------------
// bf16 MFMA GEMM tile body: 128x128 tile, BK=32, 512 thr = 8 waves (2m x 4n),
// wave tile 64x32 = 4x2 frags of 16x16x32.  Validated in round 5 (qkv).
// Fragment conventions (validated end-to-end by attn kernel):
//   A: lane m16 = row, regs = k-octet g4;  B: lane m16 = col, regs = k-octet.
//   D: col = lane&15, row = (lane>>4)*4 + reg.
// LDS pad to 40 elems/row: even 8-slot bank spread for writes and b128 reads.
// ---------------------------------------------------------------------------
__device__ __forceinline__ void mfma_gemm_core(
    const ushort* __restrict__ X, const ushort* __restrict__ W,
    f32x4 (&acc)[4][2]) {
  __shared__ ushort Al[128][40];
  __shared__ ushort Bl[128][40];
  const int tid = threadIdx.x;
  const int lane = tid & 63;
  const int w8 = tid >> 6;
  const int wm = w8 >> 2;
  const int wn = w8 & 3;
  const int m16 = lane & 15;
  const int g4 = lane >> 4;
  const int m0 = blockIdx.y << 7;
  const int n0 = blockIdx.x << 7;

  const int srow = tid >> 2;
  const int sseg = (tid & 3) << 3;
  const ushort* ap = X + (size_t)(m0 + srow) * DMODEL + sseg;
  const ushort* wp = W + (size_t)(n0 + srow) * DMODEL + sseg;

  short8 pa = *(const short8*)(ap);
  short8 pb = *(const short8*)(wp);

  for (int kt = 0; kt < DMODEL / 32; ++kt) {
    __syncthreads();
    *(short8*)&Al[srow][sseg] = pa;
    *(short8*)&Bl[srow][sseg] = pb;
    __syncthreads();
    if (kt < DMODEL / 32 - 1) {  // prefetch next tile under the MFMAs
      pa = *(const short8*)(ap + (kt + 1) * 32);
      pb = *(const short8*)(wp + (kt + 1) * 32);
    }
    short8 af[4], bf[2];
#pragma unroll
    for (int mi = 0; mi < 4; ++mi)
      af[mi] = *(const short8*)&Al[(wm << 6) + (mi << 4) + m16][g4 << 3];
#pragma unroll
    for (int ni = 0; ni < 2; ++ni)
      bf[ni] = *(const short8*)&Bl[(wn << 5) + (ni << 4) + m16][g4 << 3];
#pragma unroll
    for (int mi = 0; mi < 4; ++mi)
#pragma unroll
      for (int ni = 0; ni < 2; ++ni)
        acc[mi][ni] = __builtin_amdgcn_mfma_f32_16x16x32_bf16(
            af[mi], bf[ni], acc[mi][ni], 0, 0, 0);
  }
}

// QKV: bf16 out, Q scaled by QSCALE. Grid: (8, M/128, 3)
__global__ __launch_bounds__(512) void qkv_mfma(
    const ushort* __restrict__ X,
    const ushort* __restrict__ wqb, const ushort* __restrict__ wkb,
    const ushort* __restrict__ wvb,
    const float* __restrict__ bq, const float* __restrict__ bk,
    const float* __restrict__ bv,
    ushort* __restrict__ Qb, ushort* __restrict__ Kb,
    ushort* __restrict__ Vb) {
  const int z = blockIdx.z;
  const ushort* W = (z == 0) ? wqb : (z == 1) ? wkb : wvb;
  const float* bias = (z == 0) ? bq : (z == 1) ? bk : bv;
  ushort* Y = (z == 0) ? Qb : (z == 1) ? Kb : Vb;
  const float oscale = (z == 0) ? QSCALE : 1.0f;

  f32x4 acc[4][2];
#pragma unroll
  for (int mi = 0; mi < 4; ++mi)
#pragma unroll
    for (int ni = 0; ni < 2; ++ni) acc[mi][ni] = (f32x4){0.f, 0.f, 0.f, 0.f};
  mfma_gemm_core(X, W, acc);

  const int tid = threadIdx.x;
  const int lane = tid & 63;
  const int w8 = tid >> 6;
  const int wm = w8 >> 2, wn = w8 & 3;
  const int m16 = lane & 15, g4 = lane >> 4;
  const int m0 = blockIdx.y << 7, n0 = blockIdx.x << 7;
#pragma unroll
  for (int ni = 0; ni < 2; ++ni) {
    const int col = n0 + (wn << 5) + (ni << 4) + m16;
    const float bv4 = bias[col];
#pragma unroll
    for (int mi = 0; mi < 4; ++mi)
#pragma unroll
      for (int r = 0; r < 4; ++r) {
        const int row = m0 + (wm << 6) + (mi << 4) + (g4 << 2) + r;
        Y[(size_t)row * DMODEL + col] = f2bf((acc[mi][ni][r] + bv4) * oscale);
      }
  }
}

// O-projection: bf16 in (Ab, wob), fp32 out + bias. Grid: (8, 32, 1)
__global__ __launch_bounds__(512) void oproj_mfma(
    const ushort* __restrict__ X, const ushort* __restrict__ wob,
    const float* __restrict__ bo, float* __restrict__ Y) {
  f32x4 acc[4][2];
#pragma unroll
  for (int mi = 0; mi < 4; ++mi)
#pragma unroll
    for (int ni = 0; ni < 2; ++ni) acc[mi][ni] = (f32x4){0.f, 0.f, 0.f, 0.f};
  mfma_gemm_core(X, wob, acc);

  const int tid = threadIdx.x;
  const int lane = tid & 63;
  const int w8 = tid >> 6;
  const int wm = w8 >> 2, wn = w8 & 3;
  const int m16 = lane & 15, g4 = lane >> 4;
  const int m0 = blockIdx.y << 7, n0 = blockIdx.x << 7;
#pragma unroll
  for (int ni = 0; ni < 2; ++ni) {
    const int col = n0 + (wn << 5) + (ni << 4) + m16;
    const float bv4 = bo[col];
#pragma unroll
    for (int mi = 0; mi < 4; ++mi)
#pragma unroll
      for (int r = 0; r < 4; ++r) {
        const int row = m0 + (wm << 6) + (mi << 4) + (g4 << 2) + r;
        Y[(size_t)row * DMODEL + col] = acc[mi][ni][r] + bv4;
      }
  }
}

// ---------------------------------------------------------------------------
// MFMA flash attention (round-4 validated core + T14 prefetch + setprio).
// bf16 Q/K/V in, bf16 out. Block 512 thr = 8 waves, wave = 16 q-rows, KT=64.
// ---------------------------------------------------------------------------
__global__ __launch_bounds__(512, 4) void attn_mfma(
    const ushort* __restrict__ Q, const ushort* __restrict__ K,
    const ushort* __restrict__ V, ushort* __restrict__ O) {
  __shared__ ushort Klds[64][72];
  __shared__ ushort Vlds[64][72];
  __shared__ ushort Plds[8][16][72];

  const int tid = threadIdx.x;
  const int lane = tid & 63;
  const int wv = tid >> 6;      // wave 0..7
  const int m16 = lane & 15;
  const int g4 = lane >> 4;     // 0..3
  const int b = blockIdx.z;
  const int h = blockIdx.y;
  const int q0 = (blockIdx.x << 7) + (wv << 4);  // wave's 16-row q base

  const size_t base = ((size_t)b * SEQ) * DMODEL + h * DHEAD;  // elem offset

  // --- Q fragments (2 k-steps of 32 over DHEAD=64), rows = m16 ---
  short8 qf[2];
  {
    const ushort* qp = Q + base + (size_t)(q0 + m16) * DMODEL + (g4 << 3);
    qf[0] = *(const short8*)(qp);
    qf[1] = *(const short8*)(qp + 32);
  }

  f32x4 oacc[4];
#pragma unroll
  for (int dt = 0; dt < 4; ++dt) oacc[dt] = (f32x4){0.f, 0.f, 0.f, 0.f};
  float mrow[4] = {-1e30f, -1e30f, -1e30f, -1e30f};
  float lrow[4] = {0.f, 0.f, 0.f, 0.f};

  // staging map: 512 threads, key = tid>>3 (64), seg = tid&7 (8 x 16B)
  const int skey = tid >> 3;
  const int sseg = tid & 7;
  const ushort* kgp = K + base + (size_t)skey * DMODEL + (sseg << 3);
  const ushort* vgp = V + base + (size_t)skey * DMODEL + (sseg << 3);
  const int vswz_key = skey ^ (sseg << 3);  // conflict-free u16 scatter

  // T14: tile-0 loads issued long before first use
  short8 kvec = *(const short8*)(kgp);
  short8 vvec = *(const short8*)(vgp);

  for (int kt = 0; kt < SEQ / 64; ++kt) {
    __syncthreads();  // previous tile fully consumed
    *(short8*)&Klds[skey][sseg << 3] = kvec;
#pragma unroll
    for (int i = 0; i < 8; ++i)
      Vlds[(sseg << 3) + i][vswz_key] = ((const ushort*)&vvec)[i];
    __syncthreads();
    // T14: issue next tile's global loads now; latency hides under compute
    if (kt + 1 < SEQ / 64) {
      const size_t koff = (size_t)(kt + 1) * 64 * DMODEL;
      kvec = *(const short8*)(kgp + koff);
      vvec = *(const short8*)(vgp + koff);
    }

    // --- S = Q * K^T for 4 key sub-tiles of 16 ---
    f32x4 s[4];
#pragma unroll
    for (int kt2 = 0; kt2 < 4; ++kt2) s[kt2] = (f32x4){0.f, 0.f, 0.f, 0.f};
    __builtin_amdgcn_s_setprio(1);
#pragma unroll
    for (int ks = 0; ks < 2; ++ks) {
#pragma unroll
      for (int kt2 = 0; kt2 < 4; ++kt2) {
        const short8 kf =
            *(const short8*)&Klds[(kt2 << 4) + m16][(ks << 5) + (g4 << 3)];
        s[kt2] =
            __builtin_amdgcn_mfma_f32_16x16x32_bf16(qf[ks], kf, s[kt2], 0, 0, 0);
      }
    }
    __builtin_amdgcn_s_setprio(0);

    // --- online softmax (rows r: q = g4*4 + r), exp2 domain ---
#pragma unroll
    for (int r = 0; r < 4; ++r) {
      float t = fmaxf(fmaxf(s[0][r], s[1][r]), fmaxf(s[2][r], s[3][r]));
      t = fmaxf(t, __shfl_xor(t, 1));
      t = fmaxf(t, __shfl_xor(t, 2));
      t = fmaxf(t, __shfl_xor(t, 4));
      t = fmaxf(t, __shfl_xor(t, 8));
      const float mn = fmaxf(mrow[r], t);
      const float corr = exp2f(mrow[r] - mn);
      mrow[r] = mn;
      float ps = 0.f;
#pragma unroll
      for (int kt2 = 0; kt2 < 4; ++kt2) {
        const float p = exp2f(s[kt2][r] - mn);
        s[kt2][r] = p;
        ps += p;
      }
      ps += __shfl_xor(ps, 1);
      ps += __shfl_xor(ps, 2);
      ps += __shfl_xor(ps, 4);
      ps += __shfl_xor(ps, 8);
      lrow[r] = lrow[r] * corr + ps;
#pragma unroll
      for (int dt = 0; dt < 4; ++dt) oacc[dt][r] *= corr;
    }

    // --- P -> per-wave LDS (bf16), D-layout -> A-layout transpose ---
#pragma unroll
    for (int kt2 = 0; kt2 < 4; ++kt2)
#pragma unroll
      for (int r = 0; r < 4; ++r)
        Plds[wv][(g4 << 2) + r][(kt2 << 4) + m16] = f2bf(s[kt2][r]);

    // --- O += P * V ---
    short8 pf[2];
#pragma unroll
    for (int ks = 0; ks < 2; ++ks)
      pf[ks] = *(const short8*)&Plds[wv][m16][(ks << 5) + (g4 << 3)];
    __builtin_amdgcn_s_setprio(1);
#pragma unroll
    for (int dt = 0; dt < 4; ++dt) {
      const int d = (dt << 4) + m16;
      const int swz = (d >> 3) << 3;
#pragma unroll
      for (int ks = 0; ks < 2; ++ks) {
        const short8 vf =
            *(const short8*)&Vlds[d][((ks << 5) + (g4 << 3)) ^ swz];
        oacc[dt] =
            __builtin_amdgcn_mfma_f32_16x16x32_bf16(pf[ks], vf, oacc[dt], 0, 0, 0);
      }
    }
    __builtin_amdgcn_s_setprio(0);
  }

  // --- epilogue: O / l, bf16 out ---
#pragma unroll
  for (int r = 0; r < 4; ++r) {
    const float inv = 1.0f / lrow[r];
    const size_t row = (size_t)(q0 + (g4 << 2) + r);
    ushort* op = O + ((size_t)b * SEQ + row) * DMODEL + h * DHEAD + m16;
#pragma unroll
    for (int dt = 0; dt < 4; ++dt) op[dt << 4] = f2bf(oacc[dt][r] * inv);
  }
}

// ---------------------------------------------------------------------------
extern "C" void kernel_launch(void* const* d_in, const int* in_sizes, int n_in,
                              void* d_out, int out_size, void* d_ws,
                              size_t ws_size, hipStream_t stream) {
  const float* hs = (const float*)d_in[0];
  const float* wq = (const float*)d_in[1];
  const float* bq = (const float*)d_in[2];
  const float* wk = (const float*)d_in[3];
  const float* bk = (const float*)d_in[4];
  const float* wv = (const float*)d_in[5];
  const float* bv = (const float*)d_in[6];
  const float* wo = (const float*)d_in[7];
  const float* bo = (const float*)d_in[8];
  float* out = (float*)d_out;

  // ws layout (ushort elems): hsb 4M | wqb/wkb/wvb/wob 1M each | Qb/Kb/Vb 4M
  // | Ab 4M  -> 24M ushorts = 48 MiB
  const size_t elems = (size_t)BATCH * SEQ * DMODEL;  // 4M
  const size_t welems = (size_t)DMODEL * DMODEL;      // 1M
  ushort* hsb = (ushort*)d_ws;
  ushort* wqb = hsb + elems;
  ushort* wkb = wqb + welems;
  ushort* wvb = wkb + welems;
  ushort* wob = wvb + welems;
  ushort* Qb = wob + welems;
  ushort* Kb = Qb + elems;
  ushort* Vb = Kb + elems;
  ushort* Ab = Vb + elems;

  cast_all<<<dim3((int)(elems / (256 * 8)), 5, 1), 256, 0, stream>>>(
      hs, wq, wk, wv, wo, hsb, wqb, wkb, wvb, wob);
  qkv_mfma<<<dim3(DMODEL / 128, (BATCH * SEQ) / 128, 3), 512, 0, stream>>>(
      hsb, wqb, wkb, wvb, bq, bk, bv, Qb, Kb, Vb);
  attn_mfma<<<dim3(SEQ / 128, NH, BATCH), 512, 0, stream>>>(Qb, Kb, Vb, Ab);
  oproj_mfma<<<dim3(DMODEL / 128, (BATCH * SEQ) / 128, 1), 512, 0, stream>>>(
      Ab, wob, bo, out);
}

// Round 7
// 146.894 us; speedup vs baseline: 15.2104x; 1.2478x over previous
//
#include <hip/hip_runtime.h>
#include <math.h>

#define BATCH  2
#define SEQ    2048
#define NH     16
#define DMODEL 1024
#define DHEAD  64

typedef short short8 __attribute__((ext_vector_type(8)));
typedef float f32x4 __attribute__((ext_vector_type(4)));

// Q pre-scale: 1/sqrt(64) * log2(e)  -> softmax via exp2
#define QSCALE 0.18033688011112042f

__device__ __forceinline__ ushort f2bf(float f) {
  // round-to-nearest-even f32 -> bf16 (finite inputs only)
  unsigned int u = __builtin_bit_cast(unsigned int, f);
  u = (u + 0x7FFFu + ((u >> 16) & 1u)) >> 16;
  return (ushort)u;
}

// ---------------------------------------------------------------------------
// Cast fp32 -> bf16: z=0 hs (4M elems), z=1..4 wq/wk/wv/wo (1M each).
// ---------------------------------------------------------------------------
__global__ __launch_bounds__(256) void cast_all(
    const float* __restrict__ hs, const float* __restrict__ wq,
    const float* __restrict__ wk, const float* __restrict__ wv,
    const float* __restrict__ wo,
    ushort* __restrict__ hsb, ushort* __restrict__ wqb,
    ushort* __restrict__ wkb, ushort* __restrict__ wvb,
    ushort* __restrict__ wob) {
  const int z = blockIdx.y;
  const float* s = (z == 0) ? hs : (z == 1) ? wq : (z == 2) ? wk
                   : (z == 3) ? wv : wo;
  ushort* d = (z == 0) ? hsb : (z == 1) ? wqb : (z == 2) ? wkb
              : (z == 3) ? wvb : wob;
  const int n = (z == 0) ? BATCH * SEQ * DMODEL : DMODEL * DMODEL;
  const int i = (blockIdx.x * 256 + threadIdx.x) * 8;
  if (i < n) {
    const float4 a = *(const float4*)(s + i);
    const float4 b = *(const float4*)(s + i + 4);
    short8 o;
    o[0] = (short)f2bf(a.x); o[1] = (short)f2bf(a.y);
    o[2] = (short)f2bf(a.z); o[3] = (short)f2bf(a.w);
    o[4] = (short)f2bf(b.x); o[5] = (short)f2bf(b.y);
    o[6] = (short)f2bf(b.z); o[7] = (short)f2bf(b.w);
    *(short8*)(d + i) = o;
  }
}

// ---------------------------------------------------------------------------
// bf16 MFMA GEMM tile body: 128x128 tile, BK=32, 512 thr = 8 waves (2m x 4n),
// wave tile 64x32 = 4x2 frags of 16x16x32.  Validated rounds 5-6.
// ---------------------------------------------------------------------------
__device__ __forceinline__ void mfma_gemm_core(
    const ushort* __restrict__ X, const ushort* __restrict__ W,
    f32x4 (&acc)[4][2]) {
  __shared__ ushort Al[128][40];
  __shared__ ushort Bl[128][40];
  const int tid = threadIdx.x;
  const int lane = tid & 63;
  const int w8 = tid >> 6;
  const int wm = w8 >> 2;
  const int wn = w8 & 3;
  const int m16 = lane & 15;
  const int g4 = lane >> 4;
  const int m0 = blockIdx.y << 7;
  const int n0 = blockIdx.x << 7;

  const int srow = tid >> 2;
  const int sseg = (tid & 3) << 3;
  const ushort* ap = X + (size_t)(m0 + srow) * DMODEL + sseg;
  const ushort* wp = W + (size_t)(n0 + srow) * DMODEL + sseg;

  short8 pa = *(const short8*)(ap);
  short8 pb = *(const short8*)(wp);

  for (int kt = 0; kt < DMODEL / 32; ++kt) {
    __syncthreads();
    *(short8*)&Al[srow][sseg] = pa;
    *(short8*)&Bl[srow][sseg] = pb;
    __syncthreads();
    if (kt < DMODEL / 32 - 1) {  // prefetch next tile under the MFMAs
      pa = *(const short8*)(ap + (kt + 1) * 32);
      pb = *(const short8*)(wp + (kt + 1) * 32);
    }
    short8 af[4], bf[2];
#pragma unroll
    for (int mi = 0; mi < 4; ++mi)
      af[mi] = *(const short8*)&Al[(wm << 6) + (mi << 4) + m16][g4 << 3];
#pragma unroll
    for (int ni = 0; ni < 2; ++ni)
      bf[ni] = *(const short8*)&Bl[(wn << 5) + (ni << 4) + m16][g4 << 3];
#pragma unroll
    for (int mi = 0; mi < 4; ++mi)
#pragma unroll
      for (int ni = 0; ni < 2; ++ni)
        acc[mi][ni] = __builtin_amdgcn_mfma_f32_16x16x32_bf16(
            af[mi], bf[ni], acc[mi][ni], 0, 0, 0);
  }
}

// QKV: bf16 out, Q scaled by QSCALE. Grid: (8, M/128, 3)
__global__ __launch_bounds__(512) void qkv_mfma(
    const ushort* __restrict__ X,
    const ushort* __restrict__ wqb, const ushort* __restrict__ wkb,
    const ushort* __restrict__ wvb,
    const float* __restrict__ bq, const float* __restrict__ bk,
    const float* __restrict__ bv,
    ushort* __restrict__ Qb, ushort* __restrict__ Kb,
    ushort* __restrict__ Vb) {
  const int z = blockIdx.z;
  const ushort* W = (z == 0) ? wqb : (z == 1) ? wkb : wvb;
  const float* bias = (z == 0) ? bq : (z == 1) ? bk : bv;
  ushort* Y = (z == 0) ? Qb : (z == 1) ? Kb : Vb;
  const float oscale = (z == 0) ? QSCALE : 1.0f;

  f32x4 acc[4][2];
#pragma unroll
  for (int mi = 0; mi < 4; ++mi)
#pragma unroll
    for (int ni = 0; ni < 2; ++ni) acc[mi][ni] = (f32x4){0.f, 0.f, 0.f, 0.f};
  mfma_gemm_core(X, W, acc);

  const int tid = threadIdx.x;
  const int lane = tid & 63;
  const int w8 = tid >> 6;
  const int wm = w8 >> 2, wn = w8 & 3;
  const int m16 = lane & 15, g4 = lane >> 4;
  const int m0 = blockIdx.y << 7, n0 = blockIdx.x << 7;
#pragma unroll
  for (int ni = 0; ni < 2; ++ni) {
    const int col = n0 + (wn << 5) + (ni << 4) + m16;
    const float bv4 = bias[col];
#pragma unroll
    for (int mi = 0; mi < 4; ++mi)
#pragma unroll
      for (int r = 0; r < 4; ++r) {
        const int row = m0 + (wm << 6) + (mi << 4) + (g4 << 2) + r;
        Y[(size_t)row * DMODEL + col] = f2bf((acc[mi][ni][r] + bv4) * oscale);
      }
  }
}

// O-projection: bf16 in (Ab, wob), fp32 out + bias. Grid: (8, 32, 1)
__global__ __launch_bounds__(512) void oproj_mfma(
    const ushort* __restrict__ X, const ushort* __restrict__ wob,
    const float* __restrict__ bo, float* __restrict__ Y) {
  f32x4 acc[4][2];
#pragma unroll
  for (int mi = 0; mi < 4; ++mi)
#pragma unroll
    for (int ni = 0; ni < 2; ++ni) acc[mi][ni] = (f32x4){0.f, 0.f, 0.f, 0.f};
  mfma_gemm_core(X, wob, acc);

  const int tid = threadIdx.x;
  const int lane = tid & 63;
  const int w8 = tid >> 6;
  const int wm = w8 >> 2, wn = w8 & 3;
  const int m16 = lane & 15, g4 = lane >> 4;
  const int m0 = blockIdx.y << 7, n0 = blockIdx.x << 7;
#pragma unroll
  for (int ni = 0; ni < 2; ++ni) {
    const int col = n0 + (wn << 5) + (ni << 4) + m16;
    const float bv4 = bo[col];
#pragma unroll
    for (int mi = 0; mi < 4; ++mi)
#pragma unroll
      for (int r = 0; r < 4; ++r) {
        const int row = m0 + (wm << 6) + (mi << 4) + (g4 << 2) + r;
        Y[(size_t)row * DMODEL + col] = acc[mi][ni][r] + bv4;
      }
  }
}

// ---------------------------------------------------------------------------
// MFMA flash attention, round 7:
//  - swapped QK^T: s = mfma(kf, qf) -> lane owns ONE q-row (q = lane&15),
//    16 key-scores in registers (keys 16*kt2 + 4*g4 + r).
//    (register loads identical to the validated non-swapped variant)
//  - softmax: in-reg 16-max + 2 shfl_xor (16,32); l-sum fully in-register,
//    reduced once at the epilogue.
//  - T13 defer-max (THR=8 in exp2 domain): skip O-rescale + corr broadcast
//    when __all(tilemax <= m + 8).
//  - packed P store: 4 x ds_write_b64 per lane (swapped layout makes the
//    4 r-values key-contiguous).  PV read stays the validated b128.
//  - double-buffered K/V LDS -> ONE barrier per tile.
// bf16 Q/K/V in, bf16 out. Block 512 thr = 8 waves, wave = 16 q-rows, KT=64.
// ---------------------------------------------------------------------------
__global__ __launch_bounds__(512, 4) void attn_mfma(
    const ushort* __restrict__ Q, const ushort* __restrict__ K,
    const ushort* __restrict__ V, ushort* __restrict__ O) {
  __shared__ ushort Klds[2][64][72];
  __shared__ ushort Vlds[2][64][72];
  __shared__ ushort Plds[8][16][72];

  const int tid = threadIdx.x;
  const int lane = tid & 63;
  const int wv = tid >> 6;      // wave 0..7
  const int m16 = lane & 15;
  const int g4 = lane >> 4;     // 0..3
  const int b = blockIdx.z;
  const int h = blockIdx.y;
  const int q0 = (blockIdx.x << 7) + (wv << 4);  // wave's 16-row q base

  const size_t base = ((size_t)b * SEQ) * DMODEL + h * DHEAD;  // elem offset

  // --- Q fragments (2 k-steps of 32 over DHEAD=64), rows = m16 ---
  short8 qf[2];
  {
    const ushort* qp = Q + base + (size_t)(q0 + m16) * DMODEL + (g4 << 3);
    qf[0] = *(const short8*)(qp);
    qf[1] = *(const short8*)(qp + 32);
  }

  f32x4 oacc[4];  // [dt]: col d = dt*16+m16, rows q = g4*4+r
#pragma unroll
  for (int dt = 0; dt < 4; ++dt) oacc[dt] = (f32x4){0.f, 0.f, 0.f, 0.f};
  float mrow = -1e30f;  // running max for q = m16 (log2 domain)
  float lsum = 0.f;     // lane-partial denominator (16 of 64 keys per tile)

  // staging map: 512 threads, key = tid>>3 (64), seg = tid&7 (8 x 16B)
  const int skey = tid >> 3;
  const int sseg = tid & 7;
  const ushort* kgp = K + base + (size_t)skey * DMODEL + (sseg << 3);
  const ushort* vgp = V + base + (size_t)skey * DMODEL + (sseg << 3);
  const int vswz_key = skey ^ (sseg << 3);  // conflict-free u16 scatter

  // T14: tile-0 loads issued long before first use
  short8 kvec = *(const short8*)(kgp);
  short8 vvec = *(const short8*)(vgp);

  int p = 0;
  for (int kt = 0; kt < SEQ / 64; ++kt) {
    // stage tile kt into buffer p (prev reads of buf p drained at barrier kt-1)
    *(short8*)&Klds[p][skey][sseg << 3] = kvec;
#pragma unroll
    for (int i = 0; i < 8; ++i)
      Vlds[p][(sseg << 3) + i][vswz_key] = ((const ushort*)&vvec)[i];
    __syncthreads();  // the only barrier per tile (dbuf)
    // T14: issue next tile's global loads; latency hides under compute
    if (kt + 1 < SEQ / 64) {
      const size_t koff = (size_t)(kt + 1) * 64 * DMODEL;
      kvec = *(const short8*)(kgp + koff);
      vvec = *(const short8*)(vgp + koff);
    }

    // --- S^T = K * Q^T : s[kt2][r] = S[key=16*kt2+4*g4+r][q=m16] ---
    f32x4 s[4];
#pragma unroll
    for (int kt2 = 0; kt2 < 4; ++kt2) s[kt2] = (f32x4){0.f, 0.f, 0.f, 0.f};
    __builtin_amdgcn_s_setprio(1);
#pragma unroll
    for (int ks = 0; ks < 2; ++ks) {
#pragma unroll
      for (int kt2 = 0; kt2 < 4; ++kt2) {
        const short8 kf =
            *(const short8*)&Klds[p][(kt2 << 4) + m16][(ks << 5) + (g4 << 3)];
        s[kt2] =
            __builtin_amdgcn_mfma_f32_16x16x32_bf16(kf, qf[ks], s[kt2], 0, 0, 0);
      }
    }
    __builtin_amdgcn_s_setprio(0);

    // --- online softmax for q = m16 (exp2 domain) ---
    float t01 = fmaxf(fmaxf(s[0][0], s[0][1]), fmaxf(s[0][2], s[0][3]));
    float t11 = fmaxf(fmaxf(s[1][0], s[1][1]), fmaxf(s[1][2], s[1][3]));
    float t21 = fmaxf(fmaxf(s[2][0], s[2][1]), fmaxf(s[2][2], s[2][3]));
    float t31 = fmaxf(fmaxf(s[3][0], s[3][1]), fmaxf(s[3][2], s[3][3]));
    float tred = fmaxf(fmaxf(t01, t11), fmaxf(t21, t31));
    tred = fmaxf(tred, __shfl_xor(tred, 16));
    tred = fmaxf(tred, __shfl_xor(tred, 32));
    // T13 defer-max: only rescale when the max grew by more than 8
    if (!__all(tred <= mrow + 8.0f)) {
      const float mnew = fmaxf(mrow, tred);
      const float corr = exp2f(mrow - mnew);
      lsum *= corr;
      // broadcast corr from the lane owning q = 4*g4+r (lanes 0..15)
      const float cb0 = __shfl(corr, (g4 << 2) + 0);
      const float cb1 = __shfl(corr, (g4 << 2) + 1);
      const float cb2 = __shfl(corr, (g4 << 2) + 2);
      const float cb3 = __shfl(corr, (g4 << 2) + 3);
#pragma unroll
      for (int dt = 0; dt < 4; ++dt) {
        oacc[dt][0] *= cb0; oacc[dt][1] *= cb1;
        oacc[dt][2] *= cb2; oacc[dt][3] *= cb3;
      }
      mrow = mnew;
    }
    float ps = 0.f;
#pragma unroll
    for (int kt2 = 0; kt2 < 4; ++kt2)
#pragma unroll
      for (int r = 0; r < 4; ++r) {
        const float pv = exp2f(s[kt2][r] - mrow);
        s[kt2][r] = pv;
        ps += pv;
      }
    lsum += ps;

    // --- packed P store: P[q=m16][key=16*kt2+4*g4 + 0..3] as one b64 ---
#pragma unroll
    for (int kt2 = 0; kt2 < 4; ++kt2) {
      const uint lo = (uint)f2bf(s[kt2][0]) | ((uint)f2bf(s[kt2][1]) << 16);
      const uint hi = (uint)f2bf(s[kt2][2]) | ((uint)f2bf(s[kt2][3]) << 16);
      uint2* dst = (uint2*)&Plds[wv][m16][(kt2 << 4) + (g4 << 2)];
      *dst = make_uint2(lo, hi);
    }

    // --- O += P * V --- (same-wave LDS RAW: compiler orders via lgkmcnt)
    short8 pf[2];
#pragma unroll
    for (int ks = 0; ks < 2; ++ks)
      pf[ks] = *(const short8*)&Plds[wv][m16][(ks << 5) + (g4 << 3)];
    __builtin_amdgcn_s_setprio(1);
#pragma unroll
    for (int dt = 0; dt < 4; ++dt) {
      const int d = (dt << 4) + m16;
      const int swz = (d >> 3) << 3;
#pragma unroll
      for (int ks = 0; ks < 2; ++ks) {
        const short8 vf =
            *(const short8*)&Vlds[p][d][((ks << 5) + (g4 << 3)) ^ swz];
        oacc[dt] =
            __builtin_amdgcn_mfma_f32_16x16x32_bf16(pf[ks], vf, oacc[dt], 0, 0, 0);
      }
    }
    __builtin_amdgcn_s_setprio(0);
    p ^= 1;
  }

  // --- epilogue: reduce lsum across the 4 q-column copies, normalize ---
  lsum += __shfl_xor(lsum, 16);
  lsum += __shfl_xor(lsum, 32);
  const float inv = 1.0f / lsum;  // for q = m16, in all 4 g4 copies
  const float inv0 = __shfl(inv, (g4 << 2) + 0);
  const float inv1 = __shfl(inv, (g4 << 2) + 1);
  const float inv2 = __shfl(inv, (g4 << 2) + 2);
  const float inv3 = __shfl(inv, (g4 << 2) + 3);
  const float invr[4] = {inv0, inv1, inv2, inv3};
#pragma unroll
  for (int r = 0; r < 4; ++r) {
    const size_t row = (size_t)(q0 + (g4 << 2) + r);
    ushort* op = O + ((size_t)b * SEQ + row) * DMODEL + h * DHEAD + m16;
#pragma unroll
    for (int dt = 0; dt < 4; ++dt) op[dt << 4] = f2bf(oacc[dt][r] * invr[r]);
  }
}

// ---------------------------------------------------------------------------
extern "C" void kernel_launch(void* const* d_in, const int* in_sizes, int n_in,
                              void* d_out, int out_size, void* d_ws,
                              size_t ws_size, hipStream_t stream) {
  const float* hs = (const float*)d_in[0];
  const float* wq = (const float*)d_in[1];
  const float* bq = (const float*)d_in[2];
  const float* wk = (const float*)d_in[3];
  const float* bk = (const float*)d_in[4];
  const float* wv = (const float*)d_in[5];
  const float* bv = (const float*)d_in[6];
  const float* wo = (const float*)d_in[7];
  const float* bo = (const float*)d_in[8];
  float* out = (float*)d_out;

  // ws layout (ushort elems): hsb 4M | wqb/wkb/wvb/wob 1M each | Qb/Kb/Vb 4M
  // | Ab 4M  -> 24M ushorts = 48 MiB
  const size_t elems = (size_t)BATCH * SEQ * DMODEL;  // 4M
  const size_t welems = (size_t)DMODEL * DMODEL;      // 1M
  ushort* hsb = (ushort*)d_ws;
  ushort* wqb = hsb + elems;
  ushort* wkb = wqb + welems;
  ushort* wvb = wkb + welems;
  ushort* wob = wvb + welems;
  ushort* Qb = wob + welems;
  ushort* Kb = Qb + elems;
  ushort* Vb = Kb + elems;
  ushort* Ab = Vb + elems;

  cast_all<<<dim3((int)(elems / (256 * 8)), 5, 1), 256, 0, stream>>>(
      hs, wq, wk, wv, wo, hsb, wqb, wkb, wvb, wob);
  qkv_mfma<<<dim3(DMODEL / 128, (BATCH * SEQ) / 128, 3), 512, 0, stream>>>(
      hsb, wqb, wkb, wvb, bq, bk, bv, Qb, Kb, Vb);
  attn_mfma<<<dim3(SEQ / 128, NH, BATCH), 512, 0, stream>>>(Qb, Kb, Vb, Ab);
  oproj_mfma<<<dim3(DMODEL / 128, (BATCH * SEQ) / 128, 1), 512, 0, stream>>>(
      Ab, wob, bo, out);
}